// Round 16
// baseline (2477.950 us; speedup 1.0000x reference)
//
#include <hip/hip_runtime.h>
#include <hip/hip_bf16.h>
#include <stdint.h>

#define NB 256
#define PERIOD 30

typedef __bf16  bf16x8 __attribute__((ext_vector_type(8)));
typedef float   f32x4  __attribute__((ext_vector_type(4)));
typedef float   f32x2  __attribute__((ext_vector_type(2)));
typedef unsigned int uint4v __attribute__((ext_vector_type(4)));

__device__ __forceinline__ float frcp(float x){ return __builtin_amdgcn_rcpf(x); }

// tanh(x) = 1 - 2/(exp(2x)+1)
__device__ __forceinline__ float fast_tanh(float x){
  float e = __expf(2.0f*x);
  return fmaf(-2.0f, frcp(e + 1.0f), 1.0f);
}

__device__ __forceinline__ unsigned int f2bfbits(float x){
  union { __hip_bfloat16 b; unsigned short u; } v;
  v.b = __float2bfloat16(x);          // RNE, matches XLA convert
  return (unsigned int)v.u;
}
__device__ __forceinline__ unsigned int pack2bf(float lo, float hi){
  return f2bfbits(lo) | (f2bfbits(hi) << 16);
}

// Threefry-2x32, 20 rounds, key = (0, 42)
__device__ __forceinline__ void threefry2x32_k42(uint32_t x0, uint32_t x1,
                                                 uint32_t& o0, uint32_t& o1){
  const uint32_t ks0 = 0u, ks1 = 42u, ks2 = 0u ^ 42u ^ 0x1BD11BDAu;
  x0 += ks0; x1 += ks1;
#define TFR(rot) { x0 += x1; x1 = (x1 << (rot)) | (x1 >> (32 - (rot))); x1 ^= x0; }
  TFR(13) TFR(15) TFR(26) TFR(6)
  x0 += ks1; x1 += ks2 + 1u;
  TFR(17) TFR(29) TFR(16) TFR(24)
  x0 += ks2; x1 += ks0 + 2u;
  TFR(13) TFR(15) TFR(26) TFR(6)
  x0 += ks0; x1 += ks1 + 3u;
  TFR(17) TFR(29) TFR(16) TFR(24)
  x0 += ks1; x1 += ks2 + 4u;
  TFR(13) TFR(15) TFR(26) TFR(6)
  x0 += ks2; x1 += ks0 + 5u;
#undef TFR
  o0 = x0; o1 = x1;
}

// Mirror jax.random.normal f32 (XLA erfinv polynomial)
__device__ __forceinline__ float normal_from_bits(uint32_t bits){
  float f = __uint_as_float((bits >> 9) | 0x3f800000u) - 1.0f;
  const float lo = -0.99999994f;
  float u = fmaf(f, 2.0f, lo);
  u = fmaxf(u, lo);
  float w = -log1pf(-u*u);
  float p;
  if (w < 5.0f){
    float ww = w - 2.5f;
    p = 2.81022636e-08f;
    p = fmaf(p, ww, 3.43273939e-07f);
    p = fmaf(p, ww, -3.5233877e-06f);
    p = fmaf(p, ww, -4.39150654e-06f);
    p = fmaf(p, ww, 0.00021858087f);
    p = fmaf(p, ww, -0.00125372503f);
    p = fmaf(p, ww, -0.00417768164f);
    p = fmaf(p, ww, 0.246640727f);
    p = fmaf(p, ww, 1.50140941f);
  } else {
    float ww = sqrtf(w) - 3.0f;
    p = -0.000200214257f;
    p = fmaf(p, ww, 0.000100950558f);
    p = fmaf(p, ww, 0.00134934322f);
    p = fmaf(p, ww, -0.00367342844f);
    p = fmaf(p, ww, 0.00573950773f);
    p = fmaf(p, ww, -0.0076224613f);
    p = fmaf(p, ww, 0.00943887047f);
    p = fmaf(p, ww, 1.00167406f);
    p = fmaf(p, ww, 2.83297682f);
  }
  return 1.41421356f * (p * u);
}

// stage one sample-tile's h/u rows (owners = lanes with grp==st)
__device__ __forceinline__ void stage_tile(char* buf, int st, int grp, int colL,
    const unsigned int* hp, const unsigned int* up){
  if (grp == st){
    const int rbase = colL * 128;
    const int sw = (colL & 7) << 4;
#pragma unroll
    for (int w = 0; w < 8; ++w){
      int off = rbase + ((w * 16) ^ sw);
      *(uint4v*)(buf + off)        = uint4v{hp[w*4], hp[w*4+1], hp[w*4+2], hp[w*4+3]};
      *(uint4v*)(buf + 2048 + off) = uint4v{up[w*4], up[w*4+1], up[w*4+2], up[w*4+3]};
    }
  }
}

// MFMA net eval, C[n, sample] orientation (R15-proven). The bh/wo LDS loads
// are guarded by an opaque zero offset regenerated per st-iteration: without
// it the compiler LICMs 12 x f32x4 loads out of the st loop (+48 long-lived
// VGPR -> 216, losing the 3-waves/SIMD tier at 170).
__device__ __forceinline__ void net_eval(
    float y2, float y3,
    const float* __restrict__ W0, const float* __restrict__ b0,
    char* sAw,                        // this wave's A buffer: [2][16][128B]
    const char* __restrict__ sBb,     // B matrices [3hd][3mat][32n][128B]
    const float* __restrict__ sBH,    // [3][32] f32 bh
    const float* __restrict__ sWO,    // [3][32] f32 wo
    int colL, int grp,
    const float* bo_v,
    float& q1o, float& q2o, float& q3o,
    float& s11, float& s21, float& s31,
    float& s12, float& s22, float& s32)
{
  // ---- first layer (f32x2 pairs, per-lane = per-sample): h and u packs ----
  unsigned int hp[32], up[32];
#pragma unroll
  for (int d = 0; d < 32; ++d){
    f32x2 w0a = *(const f32x2*)(W0 + 2*d);
    f32x2 w0b = *(const f32x2*)(W0 + 64 + 2*d);
    f32x2 b0v = *(const f32x2*)(b0 + 2*d);
    f32x2 pre = y2 * w0a + (y3 * w0b + b0v);      // v_pk_fma_f32 x2
    float hA = fast_tanh(pre.x), hB = fast_tanh(pre.y);
    f32x2 h  = {hA, hB};
    f32x2 u  = 1.0f - h * h;
    hp[d] = pack2bf(hA, hB);
    up[d] = pack2bf(u.x, u.y);
  }

  float qraw[3] = {0,0,0}, Araw[3] = {0,0,0}, Braw[3] = {0,0,0};
  const int bsw = (colL & 7) << 4;

#pragma unroll 1
  for (int st = 0; st < 4; ++st){
    // opaque zero: defeats LICM of the bh/wo loads below (keeps their live
    // range inside one iteration; value is always 0)
    int zr = 0;
    asm volatile("" : "+v"(zr));

    // stage this tile in-place (same-wave program order -> overwrite safe)
    stage_tile(sAw, st, grp, colL, hp, up);

    // sample-column fragments for this tile (B-operand)
    bf16x8 afh[2], afu[2];
#pragma unroll
    for (int kt = 0; kt < 2; ++kt){
      int off = colL*128 + ((kt*64 + grp*16) ^ bsw);
      afh[kt] = *(const bf16x8*)(sAw + off);
      afu[kt] = *(const bf16x8*)(sAw + 2048 + off);
    }

#pragma unroll
    for (int hd = 0; hd < 3; ++hd){
      float aq = 0.0f, aA = 0.0f, aB = 0.0f;
#pragma unroll
      for (int nt = 0; nt < 2; ++nt){
        // B-matrix fragments (A-operand) from LDS at point of use
        bf16x8 bW[2], bA[2], bB[2];
#pragma unroll
        for (int kt = 0; kt < 2; ++kt){
          int rbase2 = (hd*96 + nt*16 + colL) * 128;
          int ko = ((kt*64 + grp*16) ^ bsw);
          bW[kt] = *(const bf16x8*)(sBb + rbase2 + ko);
          bA[kt] = *(const bf16x8*)(sBb + rbase2 + 4096 + ko);
          bB[kt] = *(const bf16x8*)(sBb + rbase2 + 8192 + ko);
        }
        // this lane's 4 n-rows: n = nt*16 + grp*4 + r  (zr = opaque 0)
        f32x4 bh4 = *(const f32x4*)(sBH + hd*32 + nt*16 + grp*4 + zr);
        f32x4 wo4 = *(const f32x4*)(sWO + hd*32 + nt*16 + grp*4 + zr);
        f32x4 cAT = bh4;                     // bh folded in via C-seed
        f32x4 cA2 = {0,0,0,0}, cA3 = {0,0,0,0};
#pragma unroll
        for (int kt = 0; kt < 2; ++kt){
          cAT = __builtin_amdgcn_mfma_f32_16x16x32_bf16(bW[kt], afh[kt], cAT, 0, 0, 0);
          cA2 = __builtin_amdgcn_mfma_f32_16x16x32_bf16(bA[kt], afu[kt], cA2, 0, 0, 0);
          cA3 = __builtin_amdgcn_mfma_f32_16x16x32_bf16(bB[kt], afu[kt], cA3, 0, 0, 0);
        }
        float t0 = fast_tanh(cAT[0]);
        float t1 = fast_tanh(cAT[1]);
        float t2 = fast_tanh(cAT[2]);
        float t3 = fast_tanh(cAT[3]);
        // q-path: wo in f32 (tanh blocks folding)
        aq = fmaf(t0, wo4[0], aq);
        aq = fmaf(t1, wo4[1], aq);
        aq = fmaf(t2, wo4[2], aq);
        aq = fmaf(t3, wo4[3], aq);
        // JVP paths: wo*SIG pre-folded into the B matrices
        float dt0 = fmaf(-t0, t0, 1.0f);
        float dt1 = fmaf(-t1, t1, 1.0f);
        float dt2 = fmaf(-t2, t2, 1.0f);
        float dt3 = fmaf(-t3, t3, 1.0f);
        aA = fmaf(dt0, cA2[0], aA);
        aA = fmaf(dt1, cA2[1], aA);
        aA = fmaf(dt2, cA2[2], aA);
        aA = fmaf(dt3, cA2[3], aA);
        aB = fmaf(dt0, cA3[0], aB);
        aB = fmaf(dt1, cA3[1], aB);
        aB = fmaf(dt2, cA3[2], aB);
        aB = fmaf(dt3, cA3[3], aB);
      }
      // cross-group reduce: n also spans the 4 lane-groups
      aq += __shfl_xor(aq, 16, 64);  aq += __shfl_xor(aq, 32, 64);
      aA += __shfl_xor(aA, 16, 64);  aA += __shfl_xor(aA, 32, 64);
      aB += __shfl_xor(aB, 16, 64);  aB += __shfl_xor(aB, 32, 64);
      // after butterfly every lane holds sample (st*16+colL)'s sum;
      // lane owns sample (grp*16+colL) -> keep when st == grp
      bool keep = (st == grp);
      qraw[hd] = keep ? aq : qraw[hd];
      Araw[hd] = keep ? aA : Araw[hd];
      Braw[hd] = keep ? aB : Braw[hd];
    }
  }

  q1o = __expf(qraw[0] + bo_v[0]);
  q2o = __expf(qraw[1] + bo_v[1]);
  q3o = __expf(qraw[2] + bo_v[2]);
  s11 = Araw[0]; s21 = Araw[1]; s31 = Araw[2];   // SIG folded into B
  s12 = Braw[0]; s22 = Braw[1]; s32 = Braw[2];
}

// NOTE: no min-waves __launch_bounds__ arg — it forces accumulator spills
// ((256,3)->210GB, (256,4)->42GB scratch writes). Natural allocation is clean.
__global__ __launch_bounds__(NB)
void sim_kernel(const float* __restrict__ Y,
  const float* __restrict__ W0,  const float* __restrict__ b0,
  const float* __restrict__ Wh1, const float* __restrict__ bh1,
  const float* __restrict__ Wo1, const float* __restrict__ bo1,
  const float* __restrict__ Wh2, const float* __restrict__ bh2,
  const float* __restrict__ Wo2, const float* __restrict__ bo2,
  const float* __restrict__ Wh3, const float* __restrict__ bh3,
  const float* __restrict__ Wo3, const float* __restrict__ bo3,
  float* __restrict__ out, int n)
{
  // B matrices: per head {Wh^T, (diag(w0a)Wh diag(wo*SIG))^T,
  // (diag(w0b)Wh diag(wo*SIG))^T}, bf16, swizzled 128B rows. 288 rows = 36 KB.
  __shared__ __align__(16) char sB[288 * 128];
  __shared__ __align__(16) char sA[4][2 * 16 * 128];   // per-wave {h,u} (16 KB)
  __shared__ __align__(16) float sBH[96];              // bh per head/n (f32)
  __shared__ __align__(16) float sWO[96];              // wo per head/n (f32)

  for (int e = threadIdx.x; e < 18432; e += NB){
    int hd   = e / 6144;
    int rem  = e - hd * 6144;
    int mat  = rem >> 11;          // 0=Wh, 1=w0a-scaled, 2=w0b-scaled
    int rem2 = rem & 2047;
    int j = rem2 >> 5, i = rem2 & 31;
    const float* W  = (hd == 0) ? Wh1 : (hd == 1) ? Wh2 : Wh3;
    const float* WO = (hd == 0) ? Wo1 : (hd == 1) ? Wo2 : Wo3;
    float wh = W[j * 32 + i];
    float sc = WO[i] * 0.03f;      // wo * SIGMA fold (JVP mats only)
    float v  = (mat == 0) ? wh
             : (mat == 1) ? W0[j] * wh * sc
                          : W0[64 + j] * wh * sc;
    int R   = hd * 96 + mat * 32 + i;
    int off = (R * 128 + j * 2) ^ ((R & 7) << 4);
    *(unsigned short*)(sB + off) = (unsigned short)f2bfbits(v);
  }
  if (threadIdx.x < 96){
    int hd = threadIdx.x >> 5, row = threadIdx.x & 31;
    const float* BH = (hd == 0) ? bh1 : (hd == 1) ? bh2 : bh3;
    const float* WO = (hd == 0) ? Wo1 : (hd == 1) ? Wo2 : Wo3;
    sBH[threadIdx.x] = BH[row];
    sWO[threadIdx.x] = WO[row];
  }
  __syncthreads();

  const int wv   = threadIdx.x >> 6;
  const int lane = threadIdx.x & 63;
  const int colL = lane & 15;
  const int grp  = lane >> 4;
  char* sAw = &sA[wv][0];

  float bo_v[3] = {bo1[0], bo2[0], bo3[0]};

  const int gid = blockIdx.x * NB + threadIdx.x;
  const int ii  = (gid < n) ? gid : (n - 1);
  const float valid = (gid < n) ? 1.0f : 0.0f;

  const float2 yv = ((const float2*)Y)[ii];
  const float y2 = yv.x, y3 = yv.y;

  const float GAMMA = 1.2f, DT = 0.005f, SIGMA = 0.03f;
  const float KAPPA = 0.2f, YBAR = 2.0f, RHO = 0.03f, Bc = 1.0f, Cc = 0.1f;

  float q1,q2,q3,s11,s21,s31,s12,s22,s32;
  net_eval(y2, y3, W0, b0, sAw, sB, sBH, sWO, colL, grp, bo_v,
           q1,q2,q3,s11,s21,s31,s12,s22,s32);
  float Y2 = y2, Y3 = y3;
  float loss = 0.0f;

  for (int t = 0; t < PERIOD; ++t){
    // --- noise: threefry rollout, counter = flat index (bit-exact) ---
    uint32_t idx0 = 2u * ((uint32_t)t * (uint32_t)n + (uint32_t)ii);
    uint32_t a0, a1, c0, c1;
    threefry2x32_k42(0u, idx0,      a0, a1);
    threefry2x32_k42(0u, idx0 + 1u, c0, c1);
    float dZ1 = 0.070710678f * normal_from_bits(a0 ^ a1);
    float dZ2 = 0.070710678f * normal_from_bits(c0 ^ c1);

    // --- step math (mirror reference, f32) ---
    float Wt  = q1 + q2 + q3;
    float q1h = q1 / Wt;
    float q2h = q2 / Wt;
    float q3h = 1.0f - q1h - q2h;
    float q1sq = q1 * q1;
    float c   = Bc*q1 - Cc*q1sq + Y2 + Y3;
    float bq  = Bc*q1 - 2.0f*Cc*q1sq;
    float sc1 = fmaf(bq, s11, SIGMA);
    float sc2 = fmaf(bq, s12, SIGMA);
    float sW1 = q1*s11 + q2*s21 + q3*s31;
    float sW2 = q1*s12 + q2*s22 + q3*s32;
    float sJ1 = 6.0f * (sc1/c - sW1/Wt);
    float sJ2 = 6.0f * (sc2/c - sW2/Wt);
    float d11 = s11*s11 + s12*s12;
    float d12 = s11*s21 + s12*s22;
    float d13 = s11*s31 + s12*s32;
    float d22 = s21*s21 + s22*s22;
    float d23 = s21*s31 + s22*s32;
    float d33 = s31*s31 + s32*s32;
    const float oneMG = 1.0f - GAMMA;   // -0.2
    float p1 = GAMMA*(q1h*d11 + q2h*d12 + q3h*d13) - oneMG*(sJ1*s11 + sJ2*s12);
    float p2 = GAMMA*(q1h*d12 + q2h*d22 + q3h*d23) - oneMG*(sJ1*s21 + sJ2*s22);
    float p3 = GAMMA*(q1h*d13 + q2h*d23 + q3h*d33) - oneMG*(sJ1*s31 + sJ2*s32);
    float muY2 = KAPPA * (YBAR - Y2);
    float muY3 = KAPPA * (YBAR - Y3);
    float r = RHO + GAMMA*(bq*(p1 - (Bc - Cc*q1)) - Cc*q1sq*d11 + muY2 + muY3)/c
                  - 1.32f*(sc1*sc1 + sc2*sc2)/(c*c);
    r = r / (1.0f - GAMMA*bq/c);
    float mu1 = r + p1 - (Bc - Cc*q1);
    float mu2 = r + p2 - Y2/q2;
    float mu3 = r + p3 - Y3/q3;
    float q1n = q1 * (1.0f + mu1*DT + s11*dZ1 + s12*dZ2);
    float q2n = q2 * (1.0f + mu2*DT + s21*dZ1 + s22*dZ2);
    float q3n = q3 * (1.0f + mu3*DT + s31*dZ1 + s32*dZ2);
    float Y2n = Y2 + muY2*DT + SIGMA*dZ1;
    float Y3n = Y3 + muY3*DT + SIGMA*dZ2;

    float qt1, qt2, qt3;
    net_eval(Y2n, Y3n, W0, b0, sAw, sB, sBH, sWO, colL, grp, bo_v,
             qt1,qt2,qt3, s11,s21,s31,s12,s22,s32);

    float e1 = q1n - qt1, e2 = q2n - qt2, e3 = q3n - qt3;
    loss += e1*e1 + e2*e2 + e3*e3;

    q1 = q1n; q2 = q2n; q3 = q3n; Y2 = Y2n; Y3 = Y3n;
  }

  loss *= valid * (1.0f / ((float)15000000));   // / (n * PERIOD)

  // --- block reduction -> one atomic per block ---
#pragma unroll
  for (int off = 32; off > 0; off >>= 1)
    loss += __shfl_down(loss, off, 64);
  __shared__ float sred[NB / 64];
  if (lane == 0) sred[wv] = loss;
  __syncthreads();
  if (threadIdx.x == 0){
    float s = 0.0f;
#pragma unroll
    for (int w = 0; w < NB / 64; ++w) s += sred[w];
    atomicAdd(out, s);
  }
}

extern "C" void kernel_launch(void* const* d_in, const int* in_sizes, int n_in,
                              void* d_out, int out_size, void* d_ws, size_t ws_size,
                              hipStream_t stream)
{
  const float* Y   = (const float*)d_in[0];
  const float* W0  = (const float*)d_in[1];
  const float* b0  = (const float*)d_in[2];
  const float* Wh1 = (const float*)d_in[3];
  const float* bh1 = (const float*)d_in[4];
  const float* Wo1 = (const float*)d_in[5];
  const float* bo1 = (const float*)d_in[6];
  const float* Wh2 = (const float*)d_in[7];
  const float* bh2 = (const float*)d_in[8];
  const float* Wo2 = (const float*)d_in[9];
  const float* bo2 = (const float*)d_in[10];
  const float* Wh3 = (const float*)d_in[11];
  const float* bh3 = (const float*)d_in[12];
  const float* Wo3 = (const float*)d_in[13];
  const float* bo3 = (const float*)d_in[14];

  const int n = in_sizes[0] / 2;

  (void)hipMemsetAsync(d_out, 0, sizeof(float), stream);

  const int grid = (n + NB - 1) / NB;
  sim_kernel<<<grid, NB, 0, stream>>>(Y,
      W0, b0, Wh1, bh1, Wo1, bo1, Wh2, bh2, Wo2, bo2, Wh3, bh3, Wo3, bo3,
      (float*)d_out, n);
}